// Round 6
// baseline (338861.743 us; speedup 1.0000x reference)
//
#include <hip/hip_runtime.h>
#include <math.h>

// Problem constants
#define NN 1024
#define MM 64
#define CC 512
#define LL 64
#define TT 8192
#define EPSF 1e-16f

// Flat output offsets (return order: seq_out, ww_h, rw_h, a_h, r_h)
#define OFF_SEQ 0
#define OFF_WW  (TT*LL)
#define OFF_RW  (OFF_WW + TT*NN)
#define OFF_A   (OFF_RW + TT*NN)
#define OFF_R   (OFF_A + TT*MM)

// d_ws float offsets
#define WSF_PRE   0
#define WSF_M     (TT*CC)
#define WSF_WCAT  (WSF_M + 32768)      // 512*272 packed [Ww | Wr | 0pad]

// LDS-only barrier (round-3 win): drains lgkmcnt but lets global ops stay in
// flight across the barrier (no vmcnt drain). "memory" clobber pins LDS ordering.
#define BAR() asm volatile("s_waitcnt lgkmcnt(0)\n\ts_barrier" ::: "memory")

__device__ __forceinline__ float sigmoid_f(float x) { return 1.0f / (1.0f + __expf(-x)); }
__device__ __forceinline__ float softplus_f(float x) { return (x > 15.0f) ? x : __logf(1.0f + __expf(x)); }
__device__ __forceinline__ float tanh_f(float x) { float e = __expf(2.0f * x); return 1.0f - 2.0f / (e + 1.0f); }
__device__ __forceinline__ float pow_f(float b, float g) { return __expf(g * __logf(b)); }  // b >= 0
__device__ __forceinline__ int bitrev4(int l) {
    return ((l & 1) << 3) | ((l & 2) << 1) | ((l & 4) >> 1) | ((l & 8) >> 3);
}

// Cross-lane XOR exchange. m=1,2 on the VALU via DPP quad_perm; m=4,8,16,32 via
// __shfl_xor (DS pipe). Round-4 erratum: permlane32_swap select was inverted —
// do not reintroduce without an assembly-verified probe.
__device__ __forceinline__ float xor_any(float v, const int m, const int lane) {
    if (m == 1)
        return __int_as_float(__builtin_amdgcn_mov_dpp(__float_as_int(v), 0xB1, 0xF, 0xF, true)); // quad_perm [1,0,3,2]
    if (m == 2)
        return __int_as_float(__builtin_amdgcn_mov_dpp(__float_as_int(v), 0x4E, 0xF, 0xF, true)); // quad_perm [2,3,0,1]
    return __shfl_xor(v, m, 64);
}

__device__ __forceinline__ float bfly64(float s, const int lane) {
    s += xor_any(s, 1, lane);
    s += xor_any(s, 2, lane);
    s += xor_any(s, 4, lane);
    s += xor_any(s, 8, lane);
    s += xor_any(s, 16, lane);
    s += xor_any(s, 32, lane);
    return s;
}

// Kernel 1: pre[t][j] = sum_i seq[t][i] * Wc[i][j] + bc[j]
__global__ void pre_kernel(const float* __restrict__ seq, const float* __restrict__ Wc,
                           const float* __restrict__ bc, float* __restrict__ pre) {
    int gid = blockIdx.x * blockDim.x + threadIdx.x;
    int t = gid >> 9;
    int j = gid & 511;
    if (t >= TT) return;
    const float* s = seq + t * LL;
    float acc = bc[j];
    #pragma unroll 8
    for (int i = 0; i < LL; ++i) acc += s[i] * Wc[i * CC + j];
    pre[gid] = acc;
}

// Kernel 1b: Wcat[512][272] = [Ww (198 cols) | Wr (70 cols) | 4 zero cols]
__global__ void pack_kernel(const float* __restrict__ Ww, const float* __restrict__ Wr,
                            float* __restrict__ Wcat) {
    int gid = blockIdx.x * 256 + threadIdx.x;
    if (gid >= 512 * 272) return;
    int r = gid / 272, c = gid - r * 272;
    float v = 0.0f;
    if (c < 198) v = Ww[r * 198 + c];
    else if (c < 268) v = Wr[r * 70 + (c - 198)];
    Wcat[gid] = v;
}

// Round-13: 512 threads (8 waves), each thread owns M rows tid and tid+512.
// Rationale: kw/e/a/kr LDS broadcast reads (64 b128/wave/step) were duplicated
// across 16 waves (~1024 ops ~ 25% of step); now read once per wave and shared
// by both rows -> broadcast ops halve. All reductions keep per-64-row grouping:
// row-b butterflies write red[*][wv+8] / wmat[wv+8], folds unchanged -> bitwise
// identical results. sh_WoT padded to stride 68 (round-5 conflict: lane-stride
// 64 floats = same bank column, 9.4M conflicts). launch_bounds(512,2) caps
// VGPR at 256 for the 128-float persistent M state.
#define WOT_S 68
__global__ __launch_bounds__(512, 2)
void ntm_kernel(
    const float* __restrict__ pre,   // [TT][CC]
    const float* __restrict__ Wc,    // [128][512]
    const float* __restrict__ Wcat,  // [512][272] packed Ww|Wr
    const float* __restrict__ br,    // [70]
    const float* __restrict__ bw,    // [198]
    const float* __restrict__ Wo,    // [64][64]
    const float* __restrict__ bo,    // [64]
    float* __restrict__ out)
{
    __shared__ __align__(16) float sh_part[4096];     // A: 8x512 ; C: 8x272
    __shared__ __align__(16) float sh_h[CC];
    __shared__ __align__(16) float sh_kw[MM];
    __shared__ __align__(16) float sh_kr[MM];
    __shared__ __align__(16) float sh_e[MM];
    __shared__ __align__(16) float sh_a[MM];
    __shared__ __align__(16) float sh_scal[16];
    __shared__ __align__(16) float sh_evbuf[NN];
    __shared__ __align__(16) float sh_wpbuf[NN];
    __shared__ __align__(16) float red[4][16];
    __shared__ __align__(16) float wmat[16][MM];
    __shared__ __align__(16) float sh_r[MM];
    __shared__ __align__(16) float sh_WoT[LL * WOT_S]; // transposed + padded stride
    __shared__ __align__(16) float sh_bo[LL];
    __shared__ __align__(16) float sh_bw[200];
    __shared__ __align__(16) float sh_br[72];
    __shared__ __align__(16) float sh_pren[CC];       // prefetched pre[t+1]

    const int tid  = threadIdx.x;
    const int lane = tid & 63;
    const int wv   = tid >> 6;          // 0..7
    const int r0   = tid;
    const int r1   = tid + 512;

    // ---- preload constants into LDS, init state ----
    for (int idx = tid; idx < MM * LL; idx += 512) {
        int i = idx >> 6, o = idx & 63;               // Wo[i][o] -> WoT[o][i]
        sh_WoT[o * WOT_S + i] = Wo[i * LL + o];
    }
    if (tid < LL)  sh_bo[tid] = bo[tid];
    if (tid < 198) sh_bw[tid] = bw[tid];
    if (tid < 70)  sh_br[tid] = br[tid];
    if (tid < MM)  sh_r[tid] = 1e-6f;
    sh_pren[tid] = pre[tid];                          // 512 threads cover CC

    float MloA[32], MloB[32];
    #pragma unroll
    for (int j = 0; j < 32; ++j) { MloA[j] = 1e-6f; MloB[j] = 1e-6f; }
    float4 mhA[8], mhB[8];
    #pragma unroll
    for (int k = 0; k < 8; ++k) {
        mhA[k] = make_float4(1e-6f, 1e-6f, 1e-6f, 1e-6f);
        mhB[k] = mhA[k];
    }
    float rownA = sqrtf(64.0f * 1e-12f), rownB = rownA;
    float wwprevA = 0.0f;                              // row tid  (none == 512)
    float wwprevB = (tid == 0) ? 1.0f : 0.0f;          // row tid+512 (row 512 = thread 0)
    float rwprevA = wwprevA, rwprevB = wwprevB;
    __syncthreads();   // init barrier: full sync (one-time)

    for (int t = 0; t < TT; ++t) {
        // ===== A: h-partials. thread=(g:128 col-groups, q:4) handling chunks q and q+4 =====
        {
            int g = tid & 127, q = tid >> 7;          // q in [0,4)
            #pragma unroll
            for (int c2 = 0; c2 < 2; ++c2) {
                int qq = q + c2 * 4;
                const float4* wbase = (const float4*)(Wc + (64 + qq * 8) * CC) + g;
                float4 ra = *(const float4*)(sh_r + qq * 8);
                float4 rb = *(const float4*)(sh_r + qq * 8 + 4);
                float rv[8] = {ra.x, ra.y, ra.z, ra.w, rb.x, rb.y, rb.z, rb.w};
                float4 acc = make_float4(0.0f, 0.0f, 0.0f, 0.0f);
                #pragma unroll
                for (int i = 0; i < 8; ++i) {
                    float4 w = wbase[i * 128];
                    acc.x += rv[i] * w.x; acc.y += rv[i] * w.y;
                    acc.z += rv[i] * w.z; acc.w += rv[i] * w.w;
                }
                ((float4*)sh_part)[qq * 128 + g] = acc;
            }
        }
        BAR();  // 1
        // ===== B: h = tanh(pre + 8 partials) — all 512 threads =====
        {
            float p0 = sh_part[tid]          + sh_part[512 + tid];
            float p1 = sh_part[1024 + tid]   + sh_part[1536 + tid];
            float p2 = sh_part[2048 + tid]   + sh_part[2560 + tid];
            float p3 = sh_part[3072 + tid]   + sh_part[3584 + tid];
            float v = sh_pren[tid] + ((p0 + p1) + (p2 + p3));
            sh_h[tid] = tanh_f(v);
        }
        BAR();  // 2
        // ===== C: ow/orr partials; 544 units on 512 threads (32 threads do 2) =====
        for (int u = tid; u < 544; u += 512) {
            int g = u % 68, q = u / 68;               // cols 4g..4g+3, rows 64q..64q+63
            const float4* wbase = (const float4*)(Wcat + (q * 64) * 272) + g;
            const float4* h4p = (const float4*)(sh_h + q * 64);
            float4 acc = make_float4(0.0f, 0.0f, 0.0f, 0.0f);
            #pragma unroll 2
            for (int i4 = 0; i4 < 16; ++i4) {
                float4 h4 = h4p[i4];
                const float4* wr = wbase + (i4 * 4) * 68;
                float4 w0 = wr[0];
                float4 w1 = wr[68];
                float4 w2 = wr[136];
                float4 w3 = wr[204];
                acc.x += h4.x * w0.x; acc.y += h4.x * w0.y; acc.z += h4.x * w0.z; acc.w += h4.x * w0.w;
                acc.x += h4.y * w1.x; acc.y += h4.y * w1.y; acc.z += h4.y * w1.z; acc.w += h4.y * w1.w;
                acc.x += h4.z * w2.x; acc.y += h4.z * w2.y; acc.z += h4.z * w2.z; acc.w += h4.z * w2.w;
                acc.x += h4.w * w3.x; acc.y += h4.w * w3.y; acc.z += h4.w * w3.z; acc.w += h4.w * w3.w;
            }
            ((float4*)sh_part)[q * 68 + g] = acc;
        }
        BAR();  // 3
        // ===== D: head transforms on wv0-5; wv6 = pre[t+1] prefetch; wv7 = K(t-1) =====
        float4 pren0, pren1;                          // live D->J on wv6 only
        #define OWV(c) ( (((sh_part[(c)] + sh_part[272 + (c)]) + (sh_part[544 + (c)] + sh_part[816 + (c)])) \
                        + ((sh_part[1088 + (c)] + sh_part[1360 + (c)]) + (sh_part[1632 + (c)] + sh_part[1904 + (c)]))) \
                        + ((c) < 198 ? sh_bw[(c)] : sh_br[(c) - 198]) )
        if (wv == 0) {
            float v = tanh_f(OWV(lane));
            sh_kw[lane] = v;
            float s2 = bfly64(v * v, lane);
            if (lane == 0) sh_scal[6] = sqrtf(s2);
        } else if (wv == 1) {
            float v = tanh_f(OWV(198 + lane));
            sh_kr[lane] = v;
            float s2 = bfly64(v * v, lane);
            if (lane == 0) sh_scal[14] = sqrtf(s2);
        } else if (wv == 2) {
            sh_e[lane] = sigmoid_f(OWV(70 + lane));
        } else if (wv == 3) {
            float v = tanh_f(OWV(134 + lane));
            sh_a[lane] = v;
            out[OFF_A + t * MM + lane] = v;
        } else if (wv == 4) {
            if (lane == 0) {
                sh_scal[0] = softplus_f(OWV(64));
                sh_scal[1] = sigmoid_f(OWV(65));
                float x0 = OWV(66), x1 = OWV(67), x2 = OWV(68);
                float mx = fmaxf(x0, fmaxf(x1, x2));
                float e0 = __expf(x0 - mx), e1 = __expf(x1 - mx), e2 = __expf(x2 - mx);
                float ss = e0 + e1 + e2;
                sh_scal[2] = e0 / ss; sh_scal[3] = e1 / ss; sh_scal[4] = e2 / ss;
                sh_scal[5] = 1.0f + softplus_f(OWV(69));
            }
        } else if (wv == 5) {
            if (lane == 0) {
                sh_scal[8] = softplus_f(OWV(198 + 64));
                sh_scal[9] = sigmoid_f(OWV(198 + 65));
                float x0 = OWV(198 + 66), x1 = OWV(198 + 67), x2 = OWV(198 + 68);
                float mx = fmaxf(x0, fmaxf(x1, x2));
                float e0 = __expf(x0 - mx), e1 = __expf(x1 - mx), e2 = __expf(x2 - mx);
                float ss = e0 + e1 + e2;
                sh_scal[10] = e0 / ss; sh_scal[11] = e1 / ss; sh_scal[12] = e2 / ss;
                sh_scal[13] = 1.0f + softplus_f(OWV(198 + 69));
            }
        } else if (wv == 6) {
            // prefetch pre[t+1] (512 floats) to regs: 64 threads x 2 float4
            if (t + 1 < TT) {
                const float4* p4 = (const float4*)(pre + (t + 1) * CC) + (tid - 384) * 2;
                pren0 = p4[0];
                pren1 = p4[1];
            }
        } else { // wv == 7: K for step t-1 (sh_r stable from J(t-1) until J(t))
            if (t > 0) {
                const float4* r4p = (const float4*)sh_r;
                const float4* wop = (const float4*)(sh_WoT + lane * WOT_S);
                float a0 = 0.0f, a1 = 0.0f;
                #pragma unroll
                for (int i4 = 0; i4 < 16; ++i4) {
                    float4 r = r4p[i4];
                    float4 w = wop[i4];
                    a0 += r.x * w.x + r.y * w.y;
                    a1 += r.z * w.z + r.w * w.w;
                }
                float acc = sh_bo[lane] + a0 + a1;
                out[OFF_SEQ + (t - 1) * LL + lane] = fminf(fmaxf(acc, 0.0f), 1.0f);
            }
        }
        #undef OWV
        BAR();  // 4

        // ===== E: write-head dots (k read shared by both rows) =====
        float betaW = sh_scal[0], gW = sh_scal[1];
        float s0W = sh_scal[2], s1W = sh_scal[3], s2W = sh_scal[4];
        float gamW = sh_scal[5], knW = sh_scal[6];
        {
            const float4* k4 = (const float4*)sh_kw;
            float a0 = 0.0f, a1 = 0.0f, a2 = 0.0f, a3 = 0.0f;
            float b0 = 0.0f, b1 = 0.0f, b2 = 0.0f, b3 = 0.0f;
            #pragma unroll
            for (int j4 = 0; j4 < 8; ++j4) {
                float4 k = k4[j4];
                a0 += MloA[4*j4]   * k.x; a1 += MloA[4*j4+1] * k.y;
                a2 += MloA[4*j4+2] * k.z; a3 += MloA[4*j4+3] * k.w;
                b0 += MloB[4*j4]   * k.x; b1 += MloB[4*j4+1] * k.y;
                b2 += MloB[4*j4+2] * k.z; b3 += MloB[4*j4+3] * k.w;
            }
            #pragma unroll
            for (int k8 = 0; k8 < 8; ++k8) {
                float4 k = k4[8 + k8];
                a0 += mhA[k8].x * k.x; a1 += mhA[k8].y * k.y;
                a2 += mhA[k8].z * k.z; a3 += mhA[k8].w * k.w;
                b0 += mhB[k8].x * k.x; b1 += mhB[k8].y * k.y;
                b2 += mhB[k8].z * k.z; b3 += mhB[k8].w * k.w;
            }
            float dotA = (a0 + a1) + (a2 + a3);
            float dotB = (b0 + b1) + (b2 + b3);
            float evA = __expf(betaW * (dotA / (rownA * knW + EPSF)));
            float evB = __expf(betaW * (dotB / (rownB * knW + EPSF)));
            sh_evbuf[r0] = evA; sh_evbuf[r1] = evB;
            sh_wpbuf[r0] = wwprevA; sh_wpbuf[r1] = wwprevB;
            float sA = bfly64(evA, lane);
            if (lane == 0) red[0][wv] = sA;
            float sB = bfly64(evB, lane);
            if (lane == 0) red[0][wv + 8] = sB;
        }
        BAR();  // 5
        // ===== F: conv + sharpen (write), both rows =====
        float wshWA, wshWB;
        {
            const float4* rp = (const float4*)red[0];
            float Sev = 0.0f;
            #pragma unroll
            for (int w4 = 0; w4 < 4; ++w4) { float4 p = rp[w4]; Sev += p.x + p.y + p.z + p.w; }
            int am1 = (r0 + NN - 1) & (NN - 1), ap1 = (r0 + 1) & (NN - 1);
            float cEVa = s0W * sh_evbuf[am1] + s1W * sh_evbuf[r0] + s2W * sh_evbuf[ap1];
            float cWPa = s0W * sh_wpbuf[am1] + s1W * sh_wpbuf[r0] + s2W * sh_wpbuf[ap1];
            float wsA = (gW / Sev) * cEVa + (1.0f - gW) * cWPa;
            wshWA = pow_f(wsA, gamW);
            int bm1 = (r1 + NN - 1) & (NN - 1), bp1 = (r1 + 1) & (NN - 1);
            float cEVb = s0W * sh_evbuf[bm1] + s1W * sh_evbuf[r1] + s2W * sh_evbuf[bp1];
            float cWPb = s0W * sh_wpbuf[bm1] + s1W * sh_wpbuf[r1] + s2W * sh_wpbuf[bp1];
            float wsB = (gW / Sev) * cEVb + (1.0f - gW) * cWPb;
            wshWB = pow_f(wsB, gamW);
            float sA = bfly64(wshWA, lane);
            if (lane == 0) red[1][wv] = sA;
            float sB = bfly64(wshWB, lane);
            if (lane == 0) red[1][wv + 8] = sB;
        }
        BAR();  // 6
        // ===== G: normalize wwn; M update + norms (e/a reads shared) =====
        {
            const float4* rp = (const float4*)red[1];
            float Swsh = 0.0f;
            #pragma unroll
            for (int w4 = 0; w4 < 4; ++w4) { float4 p = rp[w4]; Swsh += p.x + p.y + p.z + p.w; }
            float wwnA = wshWA / (Swsh + EPSF);
            float wwnB = wshWB / (Swsh + EPSF);
            out[OFF_WW + t * NN + r0] = wwnA;
            out[OFF_WW + t * NN + r1] = wwnB;
            wwprevA = wwnA; wwprevB = wwnB;
            const float4* e4p = (const float4*)sh_e;
            const float4* a4p = (const float4*)sh_a;
            float n0a = 0.0f, n1a = 0.0f, n2a = 0.0f, n3a = 0.0f;
            float n0b = 0.0f, n1b = 0.0f, n2b = 0.0f, n3b = 0.0f;
            #pragma unroll
            for (int j4 = 0; j4 < 8; ++j4) {
                float4 e = e4p[j4], a = a4p[j4];
                float m0 = MloA[4*j4]   * (1.0f - wwnA * e.x) + wwnA * a.x;
                float m1 = MloA[4*j4+1] * (1.0f - wwnA * e.y) + wwnA * a.y;
                float m2 = MloA[4*j4+2] * (1.0f - wwnA * e.z) + wwnA * a.z;
                float m3 = MloA[4*j4+3] * (1.0f - wwnA * e.w) + wwnA * a.w;
                MloA[4*j4] = m0; MloA[4*j4+1] = m1; MloA[4*j4+2] = m2; MloA[4*j4+3] = m3;
                n0a += m0 * m0; n1a += m1 * m1; n2a += m2 * m2; n3a += m3 * m3;
                float p0 = MloB[4*j4]   * (1.0f - wwnB * e.x) + wwnB * a.x;
                float p1 = MloB[4*j4+1] * (1.0f - wwnB * e.y) + wwnB * a.y;
                float p2 = MloB[4*j4+2] * (1.0f - wwnB * e.z) + wwnB * a.z;
                float p3 = MloB[4*j4+3] * (1.0f - wwnB * e.w) + wwnB * a.w;
                MloB[4*j4] = p0; MloB[4*j4+1] = p1; MloB[4*j4+2] = p2; MloB[4*j4+3] = p3;
                n0b += p0 * p0; n1b += p1 * p1; n2b += p2 * p2; n3b += p3 * p3;
            }
            #pragma unroll
            for (int k = 0; k < 8; ++k) {
                float4 e = e4p[8 + k], a = a4p[8 + k];
                float4 m = mhA[k];
                m.x = m.x * (1.0f - wwnA * e.x) + wwnA * a.x;
                m.y = m.y * (1.0f - wwnA * e.y) + wwnA * a.y;
                m.z = m.z * (1.0f - wwnA * e.z) + wwnA * a.z;
                m.w = m.w * (1.0f - wwnA * e.w) + wwnA * a.w;
                mhA[k] = m;
                n0a += m.x * m.x; n1a += m.y * m.y; n2a += m.z * m.z; n3a += m.w * m.w;
                float4 p = mhB[k];
                p.x = p.x * (1.0f - wwnB * e.x) + wwnB * a.x;
                p.y = p.y * (1.0f - wwnB * e.y) + wwnB * a.y;
                p.z = p.z * (1.0f - wwnB * e.z) + wwnB * a.z;
                p.w = p.w * (1.0f - wwnB * e.w) + wwnB * a.w;
                mhB[k] = p;
                n0b += p.x * p.x; n1b += p.y * p.y; n2b += p.z * p.z; n3b += p.w * p.w;
            }
            rownA = sqrtf((n0a + n1a) + (n2a + n3a));
            rownB = sqrtf((n0b + n1b) + (n2b + n3b));
        }

        // ===== H: read-head dots (k read shared) =====
        float betaR = sh_scal[8], gR = sh_scal[9];
        float s0R = sh_scal[10], s1R = sh_scal[11], s2R = sh_scal[12];
        float gamR = sh_scal[13], knR = sh_scal[14];
        {
            const float4* k4 = (const float4*)sh_kr;
            float a0 = 0.0f, a1 = 0.0f, a2 = 0.0f, a3 = 0.0f;
            float b0 = 0.0f, b1 = 0.0f, b2 = 0.0f, b3 = 0.0f;
            #pragma unroll
            for (int j4 = 0; j4 < 8; ++j4) {
                float4 k = k4[j4];
                a0 += MloA[4*j4]   * k.x; a1 += MloA[4*j4+1] * k.y;
                a2 += MloA[4*j4+2] * k.z; a3 += MloA[4*j4+3] * k.w;
                b0 += MloB[4*j4]   * k.x; b1 += MloB[4*j4+1] * k.y;
                b2 += MloB[4*j4+2] * k.z; b3 += MloB[4*j4+3] * k.w;
            }
            #pragma unroll
            for (int k8 = 0; k8 < 8; ++k8) {
                float4 k = k4[8 + k8];
                a0 += mhA[k8].x * k.x; a1 += mhA[k8].y * k.y;
                a2 += mhA[k8].z * k.z; a3 += mhA[k8].w * k.w;
                b0 += mhB[k8].x * k.x; b1 += mhB[k8].y * k.y;
                b2 += mhB[k8].z * k.z; b3 += mhB[k8].w * k.w;
            }
            float dotA = (a0 + a1) + (a2 + a3);
            float dotB = (b0 + b1) + (b2 + b3);
            float evA = __expf(betaR * (dotA / (rownA * knR + EPSF)));
            float evB = __expf(betaR * (dotB / (rownB * knR + EPSF)));
            sh_evbuf[r0] = evA; sh_evbuf[r1] = evB;
            sh_wpbuf[r0] = rwprevA; sh_wpbuf[r1] = rwprevB;
            float sA = bfly64(evA, lane);
            if (lane == 0) red[2][wv] = sA;
            float sB = bfly64(evB, lane);
            if (lane == 0) red[2][wv + 8] = sB;
        }
        BAR();  // 7
        // ===== I: conv + sharpen (read), both rows; transpose partials =====
        float wshRA, wshRB;
        {
            const float4* rp = (const float4*)red[2];
            float Sev = 0.0f;
            #pragma unroll
            for (int w4 = 0; w4 < 4; ++w4) { float4 p = rp[w4]; Sev += p.x + p.y + p.z + p.w; }
            int am1 = (r0 + NN - 1) & (NN - 1), ap1 = (r0 + 1) & (NN - 1);
            float cEVa = s0R * sh_evbuf[am1] + s1R * sh_evbuf[r0] + s2R * sh_evbuf[ap1];
            float cWPa = s0R * sh_wpbuf[am1] + s1R * sh_wpbuf[r0] + s2R * sh_wpbuf[ap1];
            float wsA = (gR / Sev) * cEVa + (1.0f - gR) * cWPa;
            wshRA = pow_f(wsA, gamR);
            int bm1 = (r1 + NN - 1) & (NN - 1), bp1 = (r1 + 1) & (NN - 1);
            float cEVb = s0R * sh_evbuf[bm1] + s1R * sh_evbuf[r1] + s2R * sh_evbuf[bp1];
            float cWPb = s0R * sh_wpbuf[bm1] + s1R * sh_wpbuf[r1] + s2R * sh_wpbuf[bp1];
            float wsB = (gR / Sev) * cEVb + (1.0f - gR) * cWPb;
            wshRB = pow_f(wsB, gamR);
            float sA = bfly64(wshRA, lane);
            if (lane == 0) red[3][wv] = sA;
            float sB = bfly64(wshRB, lane);
            if (lane == 0) red[3][wv + 8] = sB;

            // transpose partials: row a -> wmat[wv], row b -> wmat[wv+8]
            #pragma unroll
            for (int half = 0; half < 2; ++half) {
                const int wrow = wv + half * 8;
                const float wsh = half ? wshRB : wshRA;
                #pragma unroll
                for (int chunk = 0; chunk < 4; ++chunk) {
                    const int cb = chunk * 16;
                    float v[16];
                    if (chunk < 2) {
                        #pragma unroll
                        for (int i = 0; i < 16; ++i)
                            v[i] = wsh * (half ? MloB[chunk * 16 + i] : MloA[chunk * 16 + i]);
                    } else {
                        #pragma unroll
                        for (int k = 0; k < 4; ++k) {
                            float4 m = half ? mhB[(chunk - 2) * 4 + k] : mhA[(chunk - 2) * 4 + k];
                            v[4*k]   = wsh * m.x;
                            v[4*k+1] = wsh * m.y;
                            v[4*k+2] = wsh * m.z;
                            v[4*k+3] = wsh * m.w;
                        }
                    }
                    #pragma unroll
                    for (int st = 0; st < 4; ++st) {
                        const int m = 1 << st;
                        const int hs = 8 >> st;
                        bool hi = (lane & m) != 0;
                        #pragma unroll
                        for (int i = 0; i < 8; ++i) {
                            if (i < hs) {
                                float send = hi ? v[i] : v[i + hs];
                                float recv = xor_any(send, m, lane);
                                float keep = hi ? v[i + hs] : v[i];
                                v[i] = keep + recv;
                            }
                        }
                    }
                    float v0 = v[0];
                    v0 += xor_any(v0, 16, lane);
                    v0 += xor_any(v0, 32, lane);
                    if (lane < 16) wmat[wrow][cb + bitrev4(lane)] = v0;
                }
            }
        }
        BAR();  // 8
        // ===== J: commit prefetch; normalize rwn + finalize =====
        {
            if (wv == 6 && t + 1 < TT) {
                float4* d4 = (float4*)sh_pren + (tid - 384) * 2;
                d4[0] = pren0;
                d4[1] = pren1;
            }
            const float4* rp = (const float4*)red[3];
            float Swsh = 0.0f;
            #pragma unroll
            for (int w4 = 0; w4 < 4; ++w4) { float4 p = rp[w4]; Swsh += p.x + p.y + p.z + p.w; }
            float inv = 1.0f / (Swsh + EPSF);
            float rwnA = wshRA * inv;
            float rwnB = wshRB * inv;
            out[OFF_RW + t * NN + r0] = rwnA;
            out[OFF_RW + t * NN + r1] = rwnB;
            rwprevA = rwnA; rwprevB = rwnB;
            if (tid < MM) {
                float rv = 0.0f;
                #pragma unroll
                for (int w = 0; w < 16; ++w) rv += wmat[w][tid];
                rv *= inv;
                sh_r[tid] = rv;
                out[OFF_R + t * MM + tid] = rv;
            }
        }
        BAR();  // 9
        // (K for this step runs one step late, in phase D on wave 7)
    }

    // Epilogue: K for t = TT-1 (sh_r still holds r(TT-1))
    if (tid < LL) {
        const float4* r4p = (const float4*)sh_r;
        const float4* wop = (const float4*)(sh_WoT + tid * WOT_S);
        float a0 = 0.0f, a1 = 0.0f;
        #pragma unroll
        for (int i4 = 0; i4 < 16; ++i4) {
            float4 r = r4p[i4];
            float4 w = wop[i4];
            a0 += r.x * w.x + r.y * w.y;
            a1 += r.z * w.z + r.w * w.w;
        }
        float acc = sh_bo[tid] + a0 + a1;
        out[OFF_SEQ + (TT - 1) * LL + tid] = fminf(fmaxf(acc, 0.0f), 1.0f);
    }
}

extern "C" void kernel_launch(void* const* d_in, const int* in_sizes, int n_in,
                              void* d_out, int out_size, void* d_ws, size_t ws_size,
                              hipStream_t stream) {
    const float* seq = (const float*)d_in[0];
    const float* Wc  = (const float*)d_in[1];
    const float* bc  = (const float*)d_in[2];
    const float* Wr  = (const float*)d_in[3];
    const float* br  = (const float*)d_in[4];
    const float* Ww  = (const float*)d_in[5];
    const float* bw  = (const float*)d_in[6];
    const float* Wo  = (const float*)d_in[7];
    const float* bo  = (const float*)d_in[8];
    float* out = (float*)d_out;

    float* wsf  = (float*)d_ws;
    float* pre  = wsf + WSF_PRE;
    float* Wcat = wsf + WSF_WCAT;

    pre_kernel<<<(TT * CC) / 256, 256, 0, stream>>>(seq, Wc, bc, pre);
    pack_kernel<<<(512 * 272 + 255) / 256, 256, 0, stream>>>(Ww, Wr, Wcat);
    ntm_kernel<<<1, 512, 0, stream>>>(pre, Wc, Wcat, br, bw, Wo, bo, out);
}

// Round 7
// 134780.884 us; speedup vs baseline: 2.5142x; 2.5142x over previous
//
#include <hip/hip_runtime.h>
#include <math.h>

// Problem constants
#define NN 1024
#define MM 64
#define CC 512
#define LL 64
#define TT 8192
#define EPSF 1e-16f

// Flat output offsets (return order: seq_out, ww_h, rw_h, a_h, r_h)
#define OFF_SEQ 0
#define OFF_WW  (TT*LL)
#define OFF_RW  (OFF_WW + TT*NN)
#define OFF_A   (OFF_RW + TT*NN)
#define OFF_R   (OFF_A + TT*MM)

// d_ws float offsets
#define WSF_PRE   0
#define WSF_M     (TT*CC)
#define WSF_WCAT  (WSF_M + 32768)      // 512*272 packed [Ww | Wr | 0pad]

// LDS-only barrier (round-3 win): drains lgkmcnt but lets global ops stay in
// flight across the barrier (no vmcnt drain). "memory" clobber pins LDS ordering.
#define BAR() asm volatile("s_waitcnt lgkmcnt(0)\n\ts_barrier" ::: "memory")

__device__ __forceinline__ float sigmoid_f(float x) { return 1.0f / (1.0f + __expf(-x)); }
__device__ __forceinline__ float softplus_f(float x) { return (x > 15.0f) ? x : __logf(1.0f + __expf(x)); }
__device__ __forceinline__ float tanh_f(float x) { float e = __expf(2.0f * x); return 1.0f - 2.0f / (e + 1.0f); }
__device__ __forceinline__ float pow_f(float b, float g) { return __expf(g * __logf(b)); }  // b >= 0
__device__ __forceinline__ int bitrev4(int l) {
    return ((l & 1) << 3) | ((l & 2) << 1) | ((l & 4) >> 1) | ((l & 8) >> 3);
}

// Cross-lane XOR exchange. m=1,2 on the VALU via DPP quad_perm; m=4,8,16,32 via
// __shfl_xor (DS pipe). Round-4 erratum: permlane32_swap select was inverted —
// do not reintroduce without an assembly-verified probe.
// Round-6 erratum: 2-rows-per-thread (128 persistent floats) -> AGPR shuffling,
// 4x VALU cycles. This kernel sits at the 64-VGPR wall: never add persistent state.
__device__ __forceinline__ float xor_any(float v, const int m, const int lane) {
    if (m == 1)
        return __int_as_float(__builtin_amdgcn_mov_dpp(__float_as_int(v), 0xB1, 0xF, 0xF, true)); // quad_perm [1,0,3,2]
    if (m == 2)
        return __int_as_float(__builtin_amdgcn_mov_dpp(__float_as_int(v), 0x4E, 0xF, 0xF, true)); // quad_perm [2,3,0,1]
    return __shfl_xor(v, m, 64);
}

// Full-wave butterfly sum (all lanes get total). Same add order as the original
// shfl_xor loop; only the transport pipe for m=1,2 differs.
__device__ __forceinline__ float bfly64(float s, const int lane) {
    s += xor_any(s, 1, lane);
    s += xor_any(s, 2, lane);
    s += xor_any(s, 4, lane);
    s += xor_any(s, 8, lane);
    s += xor_any(s, 16, lane);
    s += xor_any(s, 32, lane);
    return s;
}

// Kernel 1: pre[t][j] = sum_i seq[t][i] * Wc[i][j] + bc[j]
__global__ void pre_kernel(const float* __restrict__ seq, const float* __restrict__ Wc,
                           const float* __restrict__ bc, float* __restrict__ pre) {
    int gid = blockIdx.x * blockDim.x + threadIdx.x;
    int t = gid >> 9;
    int j = gid & 511;
    if (t >= TT) return;
    const float* s = seq + t * LL;
    float acc = bc[j];
    #pragma unroll 8
    for (int i = 0; i < LL; ++i) acc += s[i] * Wc[i * CC + j];
    pre[gid] = acc;
}

// Kernel 1b: Wcat[512][272] = [Ww (198 cols) | Wr (70 cols) | 4 zero cols]
__global__ void pack_kernel(const float* __restrict__ Ww, const float* __restrict__ Wr,
                            float* __restrict__ Wcat) {
    int gid = blockIdx.x * 256 + threadIdx.x;
    if (gid >= 512 * 272) return;
    int r = gid / 272, c = gid - r * 272;
    float v = 0.0f;
    if (c < 198) v = Ww[r * 198 + c];
    else if (c < 268) v = Wr[r * 70 + (c - 198)];
    Wcat[gid] = v;
}

// Round-14 = round-12 (the 137ms winner: BAR + DPP butterflies + float4 LDS reads
// + deferred K on wave 15) with sh_WoT padded to stride 68 floats.
// Round-5 diagnosis: lane-stride 64 floats put every lane's b128 read in one bank
// group (16-way conflict per quarter-wave, 9.4M conflicts). Stride 68 = 17 float4:
// lane i hits f4 bank-group (17*i)%8 -> all 8 groups covered per 8 lanes -> 2-way
// per quarter wave = free (m136). 272B rows stay 16B-aligned.
#define WOT_S 68
__global__ __launch_bounds__(1024)
void ntm_kernel(
    const float* __restrict__ pre,   // [TT][CC]
    const float* __restrict__ Wc,    // [128][512]
    const float* __restrict__ Wcat,  // [512][272] packed Ww|Wr
    const float* __restrict__ br,    // [70]
    const float* __restrict__ bw,    // [198]
    const float* __restrict__ Wo,    // [64][64]
    const float* __restrict__ bo,    // [64]
    float* __restrict__ out)
{
    __shared__ __align__(16) float sh_part[4096];     // A: 8x512 ; C: 8x272
    __shared__ __align__(16) float sh_h[CC];
    __shared__ __align__(16) float sh_kw[MM];
    __shared__ __align__(16) float sh_kr[MM];
    __shared__ __align__(16) float sh_e[MM];
    __shared__ __align__(16) float sh_a[MM];
    __shared__ __align__(16) float sh_scal[16];
    __shared__ __align__(16) float sh_evbuf[NN];
    __shared__ __align__(16) float sh_wpbuf[NN];
    __shared__ __align__(16) float red[4][16];
    __shared__ __align__(16) float wmat[16][MM];
    __shared__ __align__(16) float sh_r[MM];
    __shared__ __align__(16) float sh_WoT[LL * WOT_S]; // transposed + padded stride
    __shared__ __align__(16) float sh_bo[LL];
    __shared__ __align__(16) float sh_bw[200];
    __shared__ __align__(16) float sh_br[72];
    __shared__ __align__(16) float sh_pren[CC];       // prefetched pre[t+1]

    const int tid  = threadIdx.x;
    const int lane = tid & 63;
    const int wv   = tid >> 6;

    // ---- preload constants into LDS, init state ----
    for (int idx = tid; idx < MM * LL; idx += NN) {
        int i = idx >> 6, o = idx & 63;               // Wo[i][o] -> WoT[o][i]
        sh_WoT[o * WOT_S + i] = Wo[i * LL + o];
    }
    if (tid < LL)  sh_bo[tid] = bo[tid];
    if (tid < 198) sh_bw[tid] = bw[tid];
    if (tid < 70)  sh_br[tid] = br[tid];
    if (tid < MM)  sh_r[tid] = 1e-6f;
    if (tid < CC)  sh_pren[tid] = pre[tid];

    float Mlo[32];
    #pragma unroll
    for (int j = 0; j < 32; ++j) Mlo[j] = 1e-6f;
    float4 mh[8];
    #pragma unroll
    for (int k = 0; k < 8; ++k) mh[k] = make_float4(1e-6f, 1e-6f, 1e-6f, 1e-6f);
    float rown = sqrtf(64.0f * 1e-12f);
    float wwprev = (tid == NN / 2) ? 1.0f : 0.0f;
    float rwprev = wwprev;
    __syncthreads();   // init barrier: full sync (one-time)

    for (int t = 0; t < TT; ++t) {
        // ===== A: h-partials, float4 col-groups. thread=(g:128 col-groups, q:8 row-chunks) =====
        {
            int g = tid & 127, q = tid >> 7;          // cols 4g..4g+3, rows 8q..8q+7 of Wc2
            const float4* wbase = (const float4*)(Wc + (64 + q * 8) * CC) + g;
            float4 ra = *(const float4*)(sh_r + q * 8);
            float4 rb = *(const float4*)(sh_r + q * 8 + 4);
            float rv[8] = {ra.x, ra.y, ra.z, ra.w, rb.x, rb.y, rb.z, rb.w};
            float4 acc = make_float4(0.0f, 0.0f, 0.0f, 0.0f);
            #pragma unroll
            for (int i = 0; i < 8; ++i) {
                float4 w = wbase[i * 128];            // next row: +512 floats = +128 float4
                acc.x += rv[i] * w.x; acc.y += rv[i] * w.y;
                acc.z += rv[i] * w.z; acc.w += rv[i] * w.w;
            }
            ((float4*)sh_part)[q * 128 + g] = acc;    // sh_part[q*512 + 4g]
        }
        BAR();  // 1
        // ===== B: h = tanh(pre + 8 partials) =====
        if (tid < CC) {
            float p0 = sh_part[tid]          + sh_part[512 + tid];
            float p1 = sh_part[1024 + tid]   + sh_part[1536 + tid];
            float p2 = sh_part[2048 + tid]   + sh_part[2560 + tid];
            float p3 = sh_part[3072 + tid]   + sh_part[3584 + tid];
            float v = sh_pren[tid] + ((p0 + p1) + (p2 + p3));
            sh_h[tid] = tanh_f(v);
        }
        BAR();  // 2
        // ===== C: ow/orr partials, float4 col-groups of Wcat. 544 threads =====
        if (tid < 544) {
            int g = tid % 68, q = tid / 68;           // cols 4g..4g+3, rows 64q..64q+63
            const float4* wbase = (const float4*)(Wcat + (q * 64) * 272) + g;
            const float4* h4p = (const float4*)(sh_h + q * 64);
            float4 acc = make_float4(0.0f, 0.0f, 0.0f, 0.0f);
            #pragma unroll 2
            for (int i4 = 0; i4 < 16; ++i4) {
                float4 h4 = h4p[i4];
                const float4* wr = wbase + (i4 * 4) * 68;
                float4 w0 = wr[0];
                float4 w1 = wr[68];
                float4 w2 = wr[136];
                float4 w3 = wr[204];
                acc.x += h4.x * w0.x; acc.y += h4.x * w0.y; acc.z += h4.x * w0.z; acc.w += h4.x * w0.w;
                acc.x += h4.y * w1.x; acc.y += h4.y * w1.y; acc.z += h4.y * w1.z; acc.w += h4.y * w1.w;
                acc.x += h4.z * w2.x; acc.y += h4.z * w2.y; acc.z += h4.z * w2.z; acc.w += h4.z * w2.w;
                acc.x += h4.w * w3.x; acc.y += h4.w * w3.y; acc.z += h4.w * w3.z; acc.w += h4.w * w3.w;
            }
            ((float4*)sh_part)[q * 68 + g] = acc;     // sh_part[q*272 + 4g]
        }
        BAR();  // 3
        // ===== D: head transforms (+ pre prefetch; + previous step's K on wave 15) =====
        float pren_v = 0.0f;
        #define OWV(c) ( (((sh_part[(c)] + sh_part[272 + (c)]) + (sh_part[544 + (c)] + sh_part[816 + (c)])) \
                        + ((sh_part[1088 + (c)] + sh_part[1360 + (c)]) + (sh_part[1632 + (c)] + sh_part[1904 + (c)]))) \
                        + ((c) < 198 ? sh_bw[(c)] : sh_br[(c) - 198]) )
        if (wv == 0) {
            float v = tanh_f(OWV(lane));
            sh_kw[lane] = v;
            float s2 = bfly64(v * v, lane);
            if (lane == 0) sh_scal[6] = sqrtf(s2);
        } else if (wv == 1) {
            float v = tanh_f(OWV(198 + lane));
            sh_kr[lane] = v;
            float s2 = bfly64(v * v, lane);
            if (lane == 0) sh_scal[14] = sqrtf(s2);
        } else if (wv == 2) {
            sh_e[lane] = sigmoid_f(OWV(70 + lane));
        } else if (wv == 3) {
            float v = tanh_f(OWV(134 + lane));
            sh_a[lane] = v;
            out[OFF_A + t * MM + lane] = v;
        } else if (wv == 4) {
            if (lane == 0) {
                sh_scal[0] = softplus_f(OWV(64));
                sh_scal[1] = sigmoid_f(OWV(65));
                float x0 = OWV(66), x1 = OWV(67), x2 = OWV(68);
                float mx = fmaxf(x0, fmaxf(x1, x2));
                float e0 = __expf(x0 - mx), e1 = __expf(x1 - mx), e2 = __expf(x2 - mx);
                float ss = e0 + e1 + e2;
                sh_scal[2] = e0 / ss; sh_scal[3] = e1 / ss; sh_scal[4] = e2 / ss;
                sh_scal[5] = 1.0f + softplus_f(OWV(69));
            }
        } else if (wv == 5) {
            if (lane == 0) {
                sh_scal[8] = softplus_f(OWV(198 + 64));
                sh_scal[9] = sigmoid_f(OWV(198 + 65));
                float x0 = OWV(198 + 66), x1 = OWV(198 + 67), x2 = OWV(198 + 68);
                float mx = fmaxf(x0, fmaxf(x1, x2));
                float e0 = __expf(x0 - mx), e1 = __expf(x1 - mx), e2 = __expf(x2 - mx);
                float ss = e0 + e1 + e2;
                sh_scal[10] = e0 / ss; sh_scal[11] = e1 / ss; sh_scal[12] = e2 / ss;
                sh_scal[13] = 1.0f + softplus_f(OWV(198 + 69));
            }
        } else if (wv >= 6 && wv < 14) {     // prefetch pre[t+1] into a REGISTER (written to LDS in J)
            if (t + 1 < TT) pren_v = pre[(t + 1) * CC + (tid - 384)];
        } else if (wv == 15) {
            // K for step t-1: sh_r (written in J(t-1)) is stable until J(t).
            if (t > 0) {
                const float4* r4p = (const float4*)sh_r;
                const float4* wop = (const float4*)(sh_WoT + lane * WOT_S);
                float a0 = 0.0f, a1 = 0.0f;
                #pragma unroll
                for (int i4 = 0; i4 < 16; ++i4) {
                    float4 r = r4p[i4];
                    float4 w = wop[i4];
                    a0 += r.x * w.x + r.y * w.y;
                    a1 += r.z * w.z + r.w * w.w;
                }
                float acc = sh_bo[lane] + a0 + a1;
                out[OFF_SEQ + (t - 1) * LL + lane] = fminf(fmaxf(acc, 0.0f), 1.0f);
            }
        }
        #undef OWV
        BAR();  // 4

        // ===== E: write-head dot + ev =====
        float betaW = sh_scal[0], gW = sh_scal[1];
        float s0W = sh_scal[2], s1W = sh_scal[3], s2W = sh_scal[4];
        float gamW = sh_scal[5], knW = sh_scal[6];
        {
            const float4* k4 = (const float4*)sh_kw;
            float d0 = 0.0f, d1 = 0.0f, d2 = 0.0f, d3 = 0.0f;
            #pragma unroll
            for (int j4 = 0; j4 < 8; ++j4) {
                float4 k = k4[j4];
                d0 += Mlo[4*j4]   * k.x;
                d1 += Mlo[4*j4+1] * k.y;
                d2 += Mlo[4*j4+2] * k.z;
                d3 += Mlo[4*j4+3] * k.w;
            }
            #pragma unroll
            for (int k8 = 0; k8 < 8; ++k8) {
                float4 k = k4[8 + k8];
                d0 += mh[k8].x * k.x;
                d1 += mh[k8].y * k.y;
                d2 += mh[k8].z * k.z;
                d3 += mh[k8].w * k.w;
            }
            float dot = (d0 + d1) + (d2 + d3);
            float sim = dot / (rown * knW + EPSF);
            float ev = __expf(betaW * sim);
            sh_evbuf[tid] = ev;
            sh_wpbuf[tid] = wwprev;
            float s = bfly64(ev, lane);
            if (lane == 0) red[0][wv] = s;
        }
        BAR();  // 5
        // ===== F: conv + sharpen (write) =====
        float wshW;
        {
            const float4* rp = (const float4*)red[0];
            float Sev = 0.0f;
            #pragma unroll
            for (int w4 = 0; w4 < 4; ++w4) { float4 p = rp[w4]; Sev += p.x + p.y + p.z + p.w; }
            int tm1 = (tid + NN - 1) & (NN - 1), tp1 = (tid + 1) & (NN - 1);
            float cEV = s0W * sh_evbuf[tm1] + s1W * sh_evbuf[tid] + s2W * sh_evbuf[tp1];
            float cWP = s0W * sh_wpbuf[tm1] + s1W * sh_wpbuf[tid] + s2W * sh_wpbuf[tp1];
            float ws = (gW / Sev) * cEV + (1.0f - gW) * cWP;
            wshW = pow_f(ws, gamW);
            float s = bfly64(wshW, lane);
            if (lane == 0) red[1][wv] = s;
        }
        BAR();  // 6
        // ===== G: normalize wwn; M update + norm =====
        {
            const float4* rp = (const float4*)red[1];
            float Swsh = 0.0f;
            #pragma unroll
            for (int w4 = 0; w4 < 4; ++w4) { float4 p = rp[w4]; Swsh += p.x + p.y + p.z + p.w; }
            float wwn = wshW / (Swsh + EPSF);
            out[OFF_WW + t * NN + tid] = wwn;
            wwprev = wwn;
            const float4* e4p = (const float4*)sh_e;
            const float4* a4p = (const float4*)sh_a;
            float n0 = 0.0f, n1 = 0.0f, n2 = 0.0f, n3 = 0.0f;
            #pragma unroll
            for (int j4 = 0; j4 < 8; ++j4) {
                float4 e = e4p[j4], a = a4p[j4];
                float m0 = Mlo[4*j4]   * (1.0f - wwn * e.x) + wwn * a.x;
                float m1 = Mlo[4*j4+1] * (1.0f - wwn * e.y) + wwn * a.y;
                float m2 = Mlo[4*j4+2] * (1.0f - wwn * e.z) + wwn * a.z;
                float m3 = Mlo[4*j4+3] * (1.0f - wwn * e.w) + wwn * a.w;
                Mlo[4*j4] = m0; Mlo[4*j4+1] = m1; Mlo[4*j4+2] = m2; Mlo[4*j4+3] = m3;
                n0 += m0 * m0; n1 += m1 * m1; n2 += m2 * m2; n3 += m3 * m3;
            }
            #pragma unroll
            for (int k = 0; k < 8; ++k) {
                float4 e = e4p[8 + k], a = a4p[8 + k];
                float4 m = mh[k];
                m.x = m.x * (1.0f - wwn * e.x) + wwn * a.x;
                m.y = m.y * (1.0f - wwn * e.y) + wwn * a.y;
                m.z = m.z * (1.0f - wwn * e.z) + wwn * a.z;
                m.w = m.w * (1.0f - wwn * e.w) + wwn * a.w;
                mh[k] = m;
                n0 += m.x * m.x; n1 += m.y * m.y; n2 += m.z * m.z; n3 += m.w * m.w;
            }
            rown = sqrtf((n0 + n1) + (n2 + n3));
        }

        // ===== H: read-head dot + ev =====
        float betaR = sh_scal[8], gR = sh_scal[9];
        float s0R = sh_scal[10], s1R = sh_scal[11], s2R = sh_scal[12];
        float gamR = sh_scal[13], knR = sh_scal[14];
        {
            const float4* k4 = (const float4*)sh_kr;
            float d0 = 0.0f, d1 = 0.0f, d2 = 0.0f, d3 = 0.0f;
            #pragma unroll
            for (int j4 = 0; j4 < 8; ++j4) {
                float4 k = k4[j4];
                d0 += Mlo[4*j4]   * k.x;
                d1 += Mlo[4*j4+1] * k.y;
                d2 += Mlo[4*j4+2] * k.z;
                d3 += Mlo[4*j4+3] * k.w;
            }
            #pragma unroll
            for (int k8 = 0; k8 < 8; ++k8) {
                float4 k = k4[8 + k8];
                d0 += mh[k8].x * k.x;
                d1 += mh[k8].y * k.y;
                d2 += mh[k8].z * k.z;
                d3 += mh[k8].w * k.w;
            }
            float dot = (d0 + d1) + (d2 + d3);
            float sim = dot / (rown * knR + EPSF);
            float ev = __expf(betaR * sim);
            sh_evbuf[tid] = ev;
            sh_wpbuf[tid] = rwprev;
            float s = bfly64(ev, lane);
            if (lane == 0) red[2][wv] = s;
        }
        BAR();  // 7
        // ===== I: conv + sharpen (read); transpose partials =====
        float wshR;
        {
            const float4* rp = (const float4*)red[2];
            float Sev = 0.0f;
            #pragma unroll
            for (int w4 = 0; w4 < 4; ++w4) { float4 p = rp[w4]; Sev += p.x + p.y + p.z + p.w; }
            int tm1 = (tid + NN - 1) & (NN - 1), tp1 = (tid + 1) & (NN - 1);
            float cEV = s0R * sh_evbuf[tm1] + s1R * sh_evbuf[tid] + s2R * sh_evbuf[tp1];
            float cWP = s0R * sh_wpbuf[tm1] + s1R * sh_wpbuf[tid] + s2R * sh_wpbuf[tp1];
            float ws = (gR / Sev) * cEV + (1.0f - gR) * cWP;
            wshR = pow_f(ws, gamR);
            float s = bfly64(wshR, lane);
            if (lane == 0) red[3][wv] = s;
            #pragma unroll
            for (int chunk = 0; chunk < 4; ++chunk) {
                const int cb = chunk * 16;
                float v[16];
                if (chunk < 2) {
                    #pragma unroll
                    for (int i = 0; i < 16; ++i) v[i] = wshR * Mlo[chunk * 16 + i];
                } else {
                    #pragma unroll
                    for (int k = 0; k < 4; ++k) {
                        float4 m = mh[(chunk - 2) * 4 + k];
                        v[4*k]   = wshR * m.x;
                        v[4*k+1] = wshR * m.y;
                        v[4*k+2] = wshR * m.z;
                        v[4*k+3] = wshR * m.w;
                    }
                }
                #pragma unroll
                for (int st = 0; st < 4; ++st) {
                    const int m = 1 << st;
                    const int hs = 8 >> st;
                    bool hi = (lane & m) != 0;
                    #pragma unroll
                    for (int i = 0; i < 8; ++i) {
                        if (i < hs) {
                            float send = hi ? v[i] : v[i + hs];
                            float recv = xor_any(send, m, lane);
                            float keep = hi ? v[i + hs] : v[i];
                            v[i] = keep + recv;
                        }
                    }
                }
                float v0 = v[0];
                v0 += xor_any(v0, 16, lane);
                v0 += xor_any(v0, 32, lane);
                if (lane < 16) wmat[wv][cb + bitrev4(lane)] = v0;
            }
        }
        BAR();  // 8
        // ===== J: normalize rwn + finalize; commit pre[t+1] prefetch to LDS =====
        {
            if (wv >= 6 && wv < 14 && t + 1 < TT) sh_pren[tid - 384] = pren_v;
            const float4* rp = (const float4*)red[3];
            float Swsh = 0.0f;
            #pragma unroll
            for (int w4 = 0; w4 < 4; ++w4) { float4 p = rp[w4]; Swsh += p.x + p.y + p.z + p.w; }
            float inv = 1.0f / (Swsh + EPSF);
            float rwn = wshR * inv;
            out[OFF_RW + t * NN + tid] = rwn;
            rwprev = rwn;
            if (tid < MM) {
                float rv = 0.0f;
                #pragma unroll
                for (int w = 0; w < 16; ++w) rv += wmat[w][tid];
                rv *= inv;
                sh_r[tid] = rv;
                out[OFF_R + t * MM + tid] = rv;
            }
        }
        BAR();  // 9
        // (K for this step runs one step late, in phase D on wave 15)
    }

    // Epilogue: K for t = TT-1 (sh_r still holds r(TT-1))
    if (tid < LL) {
        const float4* r4p = (const float4*)sh_r;
        const float4* wop = (const float4*)(sh_WoT + tid * WOT_S);
        float a0 = 0.0f, a1 = 0.0f;
        #pragma unroll
        for (int i4 = 0; i4 < 16; ++i4) {
            float4 r = r4p[i4];
            float4 w = wop[i4];
            a0 += r.x * w.x + r.y * w.y;
            a1 += r.z * w.z + r.w * w.w;
        }
        float acc = sh_bo[tid] + a0 + a1;
        out[OFF_SEQ + (TT - 1) * LL + tid] = fminf(fmaxf(acc, 0.0f), 1.0f);
    }
}

extern "C" void kernel_launch(void* const* d_in, const int* in_sizes, int n_in,
                              void* d_out, int out_size, void* d_ws, size_t ws_size,
                              hipStream_t stream) {
    const float* seq = (const float*)d_in[0];
    const float* Wc  = (const float*)d_in[1];
    const float* bc  = (const float*)d_in[2];
    const float* Wr  = (const float*)d_in[3];
    const float* br  = (const float*)d_in[4];
    const float* Ww  = (const float*)d_in[5];
    const float* bw  = (const float*)d_in[6];
    const float* Wo  = (const float*)d_in[7];
    const float* bo  = (const float*)d_in[8];
    float* out = (float*)d_out;

    float* wsf  = (float*)d_ws;
    float* pre  = wsf + WSF_PRE;
    float* Wcat = wsf + WSF_WCAT;

    pre_kernel<<<(TT * CC) / 256, 256, 0, stream>>>(seq, Wc, bc, pre);
    pack_kernel<<<(512 * 272 + 255) / 256, 256, 0, stream>>>(Ww, Wr, Wcat);
    ntm_kernel<<<1, 1024, 0, stream>>>(pre, Wc, Wcat, br, bw, Wo, bo, out);
}

// Round 8
// 129412.280 us; speedup vs baseline: 2.6185x; 1.0415x over previous
//
#include <hip/hip_runtime.h>
#include <math.h>

// Problem constants
#define NN 1024
#define MM 64
#define CC 512
#define LL 64
#define TT 8192
#define EPSF 1e-16f

// Flat output offsets (return order: seq_out, ww_h, rw_h, a_h, r_h)
#define OFF_SEQ 0
#define OFF_WW  (TT*LL)
#define OFF_RW  (OFF_WW + TT*NN)
#define OFF_A   (OFF_RW + TT*NN)
#define OFF_R   (OFF_A + TT*MM)

// d_ws float offsets
#define WSF_PRE   0
#define WSF_M     (TT*CC)
#define WSF_WCAT  (WSF_M + 32768)      // 512*272 packed [Ww | Wr | 0pad]

// LDS-only barrier (round-3 win): drains lgkmcnt but lets global ops stay in
// flight across the barrier (no vmcnt drain). "memory" clobber pins LDS ordering.
#define BAR() asm volatile("s_waitcnt lgkmcnt(0)\n\ts_barrier" ::: "memory")

__device__ __forceinline__ float sigmoid_f(float x) { return 1.0f / (1.0f + __expf(-x)); }
__device__ __forceinline__ float softplus_f(float x) { return (x > 15.0f) ? x : __logf(1.0f + __expf(x)); }
__device__ __forceinline__ float tanh_f(float x) { float e = __expf(2.0f * x); return 1.0f - 2.0f / (e + 1.0f); }
__device__ __forceinline__ float pow_f(float b, float g) { return __expf(g * __logf(b)); }  // b >= 0
__device__ __forceinline__ int bitrev4(int l) {
    return ((l & 1) << 3) | ((l & 2) << 1) | ((l & 4) >> 1) | ((l & 8) >> 3);
}

// Cross-lane XOR exchange (used by the I-transpose network only). m=1,2 on the
// VALU via DPP quad_perm; m=4,8,16,32 via __shfl_xor (DS pipe, proven correct).
// Round-4 erratum: permlane32_swap select was inverted — do not reintroduce
// without an assembly-verified probe.
// Round-6 erratum: 2-rows-per-thread (128 persistent floats) -> AGPR shuffling,
// 4x VALU cycles. This kernel sits at the 64-VGPR wall: never add persistent state.
__device__ __forceinline__ float xor_any(float v, const int m, const int lane) {
    if (m == 1)
        return __int_as_float(__builtin_amdgcn_mov_dpp(__float_as_int(v), 0xB1, 0xF, 0xF, true)); // quad_perm [1,0,3,2]
    if (m == 2)
        return __int_as_float(__builtin_amdgcn_mov_dpp(__float_as_int(v), 0x4E, 0xF, 0xF, true)); // quad_perm [2,3,0,1]
    return __shfl_xor(v, m, 64);
}

// Round-8: pure-sum wave reduction with ZERO DS ops (classic GCN DPP idiom):
// row_shr:1/2/4/8 builds per-16-row sums (invalid-source lanes add 0 via old=0),
// row_bcast:15 folds row0->row1 / row2->row3, row_bcast:31 folds halves.
// TOTAL LANDS IN LANE 63 (not lane 0). Reassociates the sum vs the old xor
// butterfly -> absmax may move ~1 bf16 ulp (threshold headroom 4.3x).
template<int CTRL>
__device__ __forceinline__ float dpp_add(float s) {
    int sh = __builtin_amdgcn_update_dpp(0, __float_as_int(s), CTRL, 0xF, 0xF, false);
    return s + __int_as_float(sh);
}
__device__ __forceinline__ float rowsum64(float s) {
    s = dpp_add<0x111>(s);   // row_shr:1
    s = dpp_add<0x112>(s);   // row_shr:2
    s = dpp_add<0x114>(s);   // row_shr:4
    s = dpp_add<0x118>(s);   // row_shr:8
    s = dpp_add<0x142>(s);   // row_bcast:15
    s = dpp_add<0x143>(s);   // row_bcast:31
    return s;                // lane 63 holds the 64-lane total
}

// Kernel 1: pre[t][j] = sum_i seq[t][i] * Wc[i][j] + bc[j]
__global__ void pre_kernel(const float* __restrict__ seq, const float* __restrict__ Wc,
                           const float* __restrict__ bc, float* __restrict__ pre) {
    int gid = blockIdx.x * blockDim.x + threadIdx.x;
    int t = gid >> 9;
    int j = gid & 511;
    if (t >= TT) return;
    const float* s = seq + t * LL;
    float acc = bc[j];
    #pragma unroll 8
    for (int i = 0; i < LL; ++i) acc += s[i] * Wc[i * CC + j];
    pre[gid] = acc;
}

// Kernel 1b: Wcat[512][272] = [Ww (198 cols) | Wr (70 cols) | 4 zero cols]
__global__ void pack_kernel(const float* __restrict__ Ww, const float* __restrict__ Wr,
                            float* __restrict__ Wcat) {
    int gid = blockIdx.x * 256 + threadIdx.x;
    if (gid >= 512 * 272) return;
    int r = gid / 272, c = gid - r * 272;
    float v = 0.0f;
    if (c < 198) v = Ww[r * 198 + c];
    else if (c < 268) v = Wr[r * 70 + (c - 198)];
    Wcat[gid] = v;
}

// Round-15 = round-14 (132ms floor) + three DS-pipe cuts:
//  (1) pure-sum butterflies (D x2, E, F, H, I-red) -> rowsum64 DPP reduction
//      (zero DS ops; lane 63 writes). -264 DS wave-ops/step.
//  (2) evbuf/wpbuf packed as float2 sh_evwp: 1 b64 write + 3 b64 reads instead
//      of 2 b32 writes + 6 b32 reads. Bitwise-identical values. -128 DS ops.
//  (3) deferred K(t-1) moved from phase D to phase C's idle waves (tid>=960):
//      C is L2-BW-bound with an idle DS pipe, so K's 32 b128 reads hide there;
//      D loses its longest straggler.
#define WOT_S 68
__global__ __launch_bounds__(1024)
void ntm_kernel(
    const float* __restrict__ pre,   // [TT][CC]
    const float* __restrict__ Wc,    // [128][512]
    const float* __restrict__ Wcat,  // [512][272] packed Ww|Wr
    const float* __restrict__ br,    // [70]
    const float* __restrict__ bw,    // [198]
    const float* __restrict__ Wo,    // [64][64]
    const float* __restrict__ bo,    // [64]
    float* __restrict__ out)
{
    __shared__ __align__(16) float sh_part[4096];     // A: 8x512 ; C: 8x272
    __shared__ __align__(16) float sh_h[CC];
    __shared__ __align__(16) float sh_kw[MM];
    __shared__ __align__(16) float sh_kr[MM];
    __shared__ __align__(16) float sh_e[MM];
    __shared__ __align__(16) float sh_a[MM];
    __shared__ __align__(16) float sh_scal[16];
    __shared__ __align__(16) float2 sh_evwp[NN];      // (ev, w_prev) pairs
    __shared__ __align__(16) float red[4][16];
    __shared__ __align__(16) float wmat[16][MM];
    __shared__ __align__(16) float sh_r[MM];
    __shared__ __align__(16) float sh_WoT[LL * WOT_S]; // transposed + padded stride
    __shared__ __align__(16) float sh_bo[LL];
    __shared__ __align__(16) float sh_bw[200];
    __shared__ __align__(16) float sh_br[72];
    __shared__ __align__(16) float sh_pren[CC];       // prefetched pre[t+1]

    const int tid  = threadIdx.x;
    const int lane = tid & 63;
    const int wv   = tid >> 6;

    // ---- preload constants into LDS, init state ----
    for (int idx = tid; idx < MM * LL; idx += NN) {
        int i = idx >> 6, o = idx & 63;               // Wo[i][o] -> WoT[o][i]
        sh_WoT[o * WOT_S + i] = Wo[i * LL + o];
    }
    if (tid < LL)  sh_bo[tid] = bo[tid];
    if (tid < 198) sh_bw[tid] = bw[tid];
    if (tid < 70)  sh_br[tid] = br[tid];
    if (tid < MM)  sh_r[tid] = 1e-6f;
    if (tid < CC)  sh_pren[tid] = pre[tid];

    float Mlo[32];
    #pragma unroll
    for (int j = 0; j < 32; ++j) Mlo[j] = 1e-6f;
    float4 mh[8];
    #pragma unroll
    for (int k = 0; k < 8; ++k) mh[k] = make_float4(1e-6f, 1e-6f, 1e-6f, 1e-6f);
    float rown = sqrtf(64.0f * 1e-12f);
    float wwprev = (tid == NN / 2) ? 1.0f : 0.0f;
    float rwprev = wwprev;
    __syncthreads();   // init barrier: full sync (one-time)

    for (int t = 0; t < TT; ++t) {
        // ===== A: h-partials, float4 col-groups. thread=(g:128 col-groups, q:8 row-chunks) =====
        {
            int g = tid & 127, q = tid >> 7;          // cols 4g..4g+3, rows 8q..8q+7 of Wc2
            const float4* wbase = (const float4*)(Wc + (64 + q * 8) * CC) + g;
            float4 ra = *(const float4*)(sh_r + q * 8);
            float4 rb = *(const float4*)(sh_r + q * 8 + 4);
            float rv[8] = {ra.x, ra.y, ra.z, ra.w, rb.x, rb.y, rb.z, rb.w};
            float4 acc = make_float4(0.0f, 0.0f, 0.0f, 0.0f);
            #pragma unroll
            for (int i = 0; i < 8; ++i) {
                float4 w = wbase[i * 128];            // next row: +512 floats = +128 float4
                acc.x += rv[i] * w.x; acc.y += rv[i] * w.y;
                acc.z += rv[i] * w.z; acc.w += rv[i] * w.w;
            }
            ((float4*)sh_part)[q * 128 + g] = acc;    // sh_part[q*512 + 4g]
        }
        BAR();  // 1
        // ===== B: h = tanh(pre + 8 partials) =====
        if (tid < CC) {
            float p0 = sh_part[tid]          + sh_part[512 + tid];
            float p1 = sh_part[1024 + tid]   + sh_part[1536 + tid];
            float p2 = sh_part[2048 + tid]   + sh_part[2560 + tid];
            float p3 = sh_part[3072 + tid]   + sh_part[3584 + tid];
            float v = sh_pren[tid] + ((p0 + p1) + (p2 + p3));
            sh_h[tid] = tanh_f(v);
        }
        BAR();  // 2
        // ===== C: ow/orr partials (544 threads); K(t-1) on wave 15 (idle here) =====
        if (tid < 544) {
            int g = tid % 68, q = tid / 68;           // cols 4g..4g+3, rows 64q..64q+63
            const float4* wbase = (const float4*)(Wcat + (q * 64) * 272) + g;
            const float4* h4p = (const float4*)(sh_h + q * 64);
            float4 acc = make_float4(0.0f, 0.0f, 0.0f, 0.0f);
            #pragma unroll 2
            for (int i4 = 0; i4 < 16; ++i4) {
                float4 h4 = h4p[i4];
                const float4* wr = wbase + (i4 * 4) * 68;
                float4 w0 = wr[0];
                float4 w1 = wr[68];
                float4 w2 = wr[136];
                float4 w3 = wr[204];
                acc.x += h4.x * w0.x; acc.y += h4.x * w0.y; acc.z += h4.x * w0.z; acc.w += h4.x * w0.w;
                acc.x += h4.y * w1.x; acc.y += h4.y * w1.y; acc.z += h4.y * w1.z; acc.w += h4.y * w1.w;
                acc.x += h4.z * w2.x; acc.y += h4.z * w2.y; acc.z += h4.z * w2.z; acc.w += h4.z * w2.w;
                acc.x += h4.w * w3.x; acc.y += h4.w * w3.y; acc.z += h4.w * w3.z; acc.w += h4.w * w3.w;
            }
            ((float4*)sh_part)[q * 68 + g] = acc;     // sh_part[q*272 + 4g]
        } else if (wv == 15) {
            // K for step t-1: sh_r (written in J(t-1)) and sh_WoT are stable
            // through C; the DS pipe is idle while C streams from L2.
            if (t > 0) {
                const float4* r4p = (const float4*)sh_r;
                const float4* wop = (const float4*)(sh_WoT + lane * WOT_S);
                float a0 = 0.0f, a1 = 0.0f;
                #pragma unroll
                for (int i4 = 0; i4 < 16; ++i4) {
                    float4 r = r4p[i4];
                    float4 w = wop[i4];
                    a0 += r.x * w.x + r.y * w.y;
                    a1 += r.z * w.z + r.w * w.w;
                }
                float acc = sh_bo[lane] + a0 + a1;
                out[OFF_SEQ + (t - 1) * LL + lane] = fminf(fmaxf(acc, 0.0f), 1.0f);
            }
        }
        BAR();  // 3
        // ===== D: head transforms (+ pre prefetch) =====
        float pren_v = 0.0f;
        #define OWV(c) ( (((sh_part[(c)] + sh_part[272 + (c)]) + (sh_part[544 + (c)] + sh_part[816 + (c)])) \
                        + ((sh_part[1088 + (c)] + sh_part[1360 + (c)]) + (sh_part[1632 + (c)] + sh_part[1904 + (c)]))) \
                        + ((c) < 198 ? sh_bw[(c)] : sh_br[(c) - 198]) )
        if (wv == 0) {
            float v = tanh_f(OWV(lane));
            sh_kw[lane] = v;
            float s2 = rowsum64(v * v);
            if (lane == 63) sh_scal[6] = sqrtf(s2);
        } else if (wv == 1) {
            float v = tanh_f(OWV(198 + lane));
            sh_kr[lane] = v;
            float s2 = rowsum64(v * v);
            if (lane == 63) sh_scal[14] = sqrtf(s2);
        } else if (wv == 2) {
            sh_e[lane] = sigmoid_f(OWV(70 + lane));
        } else if (wv == 3) {
            float v = tanh_f(OWV(134 + lane));
            sh_a[lane] = v;
            out[OFF_A + t * MM + lane] = v;
        } else if (wv == 4) {
            if (lane == 0) {
                sh_scal[0] = softplus_f(OWV(64));
                sh_scal[1] = sigmoid_f(OWV(65));
                float x0 = OWV(66), x1 = OWV(67), x2 = OWV(68);
                float mx = fmaxf(x0, fmaxf(x1, x2));
                float e0 = __expf(x0 - mx), e1 = __expf(x1 - mx), e2 = __expf(x2 - mx);
                float ss = e0 + e1 + e2;
                sh_scal[2] = e0 / ss; sh_scal[3] = e1 / ss; sh_scal[4] = e2 / ss;
                sh_scal[5] = 1.0f + softplus_f(OWV(69));
            }
        } else if (wv == 5) {
            if (lane == 0) {
                sh_scal[8] = softplus_f(OWV(198 + 64));
                sh_scal[9] = sigmoid_f(OWV(198 + 65));
                float x0 = OWV(198 + 66), x1 = OWV(198 + 67), x2 = OWV(198 + 68);
                float mx = fmaxf(x0, fmaxf(x1, x2));
                float e0 = __expf(x0 - mx), e1 = __expf(x1 - mx), e2 = __expf(x2 - mx);
                float ss = e0 + e1 + e2;
                sh_scal[10] = e0 / ss; sh_scal[11] = e1 / ss; sh_scal[12] = e2 / ss;
                sh_scal[13] = 1.0f + softplus_f(OWV(198 + 69));
            }
        } else if (wv >= 6 && wv < 14) {     // prefetch pre[t+1] into a REGISTER (written to LDS in J)
            if (t + 1 < TT) pren_v = pre[(t + 1) * CC + (tid - 384)];
        }
        #undef OWV
        BAR();  // 4

        // ===== E: write-head dot + ev =====
        float betaW = sh_scal[0], gW = sh_scal[1];
        float s0W = sh_scal[2], s1W = sh_scal[3], s2W = sh_scal[4];
        float gamW = sh_scal[5], knW = sh_scal[6];
        {
            const float4* k4 = (const float4*)sh_kw;
            float d0 = 0.0f, d1 = 0.0f, d2 = 0.0f, d3 = 0.0f;
            #pragma unroll
            for (int j4 = 0; j4 < 8; ++j4) {
                float4 k = k4[j4];
                d0 += Mlo[4*j4]   * k.x;
                d1 += Mlo[4*j4+1] * k.y;
                d2 += Mlo[4*j4+2] * k.z;
                d3 += Mlo[4*j4+3] * k.w;
            }
            #pragma unroll
            for (int k8 = 0; k8 < 8; ++k8) {
                float4 k = k4[8 + k8];
                d0 += mh[k8].x * k.x;
                d1 += mh[k8].y * k.y;
                d2 += mh[k8].z * k.z;
                d3 += mh[k8].w * k.w;
            }
            float dot = (d0 + d1) + (d2 + d3);
            float sim = dot / (rown * knW + EPSF);
            float ev = __expf(betaW * sim);
            sh_evwp[tid] = make_float2(ev, wwprev);
            float s = rowsum64(ev);
            if (lane == 63) red[0][wv] = s;
        }
        BAR();  // 5
        // ===== F: conv + sharpen (write) =====
        float wshW;
        {
            const float4* rp = (const float4*)red[0];
            float Sev = 0.0f;
            #pragma unroll
            for (int w4 = 0; w4 < 4; ++w4) { float4 p = rp[w4]; Sev += p.x + p.y + p.z + p.w; }
            int tm1 = (tid + NN - 1) & (NN - 1), tp1 = (tid + 1) & (NN - 1);
            float2 em1 = sh_evwp[tm1], ec = sh_evwp[tid], ep1 = sh_evwp[tp1];
            float cEV = s0W * em1.x + s1W * ec.x + s2W * ep1.x;
            float cWP = s0W * em1.y + s1W * ec.y + s2W * ep1.y;
            float ws = (gW / Sev) * cEV + (1.0f - gW) * cWP;
            wshW = pow_f(ws, gamW);
            float s = rowsum64(wshW);
            if (lane == 63) red[1][wv] = s;
        }
        BAR();  // 6
        // ===== G: normalize wwn; M update + norm =====
        {
            const float4* rp = (const float4*)red[1];
            float Swsh = 0.0f;
            #pragma unroll
            for (int w4 = 0; w4 < 4; ++w4) { float4 p = rp[w4]; Swsh += p.x + p.y + p.z + p.w; }
            float wwn = wshW / (Swsh + EPSF);
            out[OFF_WW + t * NN + tid] = wwn;
            wwprev = wwn;
            const float4* e4p = (const float4*)sh_e;
            const float4* a4p = (const float4*)sh_a;
            float n0 = 0.0f, n1 = 0.0f, n2 = 0.0f, n3 = 0.0f;
            #pragma unroll
            for (int j4 = 0; j4 < 8; ++j4) {
                float4 e = e4p[j4], a = a4p[j4];
                float m0 = Mlo[4*j4]   * (1.0f - wwn * e.x) + wwn * a.x;
                float m1 = Mlo[4*j4+1] * (1.0f - wwn * e.y) + wwn * a.y;
                float m2 = Mlo[4*j4+2] * (1.0f - wwn * e.z) + wwn * a.z;
                float m3 = Mlo[4*j4+3] * (1.0f - wwn * e.w) + wwn * a.w;
                Mlo[4*j4] = m0; Mlo[4*j4+1] = m1; Mlo[4*j4+2] = m2; Mlo[4*j4+3] = m3;
                n0 += m0 * m0; n1 += m1 * m1; n2 += m2 * m2; n3 += m3 * m3;
            }
            #pragma unroll
            for (int k = 0; k < 8; ++k) {
                float4 e = e4p[8 + k], a = a4p[8 + k];
                float4 m = mh[k];
                m.x = m.x * (1.0f - wwn * e.x) + wwn * a.x;
                m.y = m.y * (1.0f - wwn * e.y) + wwn * a.y;
                m.z = m.z * (1.0f - wwn * e.z) + wwn * a.z;
                m.w = m.w * (1.0f - wwn * e.w) + wwn * a.w;
                mh[k] = m;
                n0 += m.x * m.x; n1 += m.y * m.y; n2 += m.z * m.z; n3 += m.w * m.w;
            }
            rown = sqrtf((n0 + n1) + (n2 + n3));
        }

        // ===== H: read-head dot + ev =====
        float betaR = sh_scal[8], gR = sh_scal[9];
        float s0R = sh_scal[10], s1R = sh_scal[11], s2R = sh_scal[12];
        float gamR = sh_scal[13], knR = sh_scal[14];
        {
            const float4* k4 = (const float4*)sh_kr;
            float d0 = 0.0f, d1 = 0.0f, d2 = 0.0f, d3 = 0.0f;
            #pragma unroll
            for (int j4 = 0; j4 < 8; ++j4) {
                float4 k = k4[j4];
                d0 += Mlo[4*j4]   * k.x;
                d1 += Mlo[4*j4+1] * k.y;
                d2 += Mlo[4*j4+2] * k.z;
                d3 += Mlo[4*j4+3] * k.w;
            }
            #pragma unroll
            for (int k8 = 0; k8 < 8; ++k8) {
                float4 k = k4[8 + k8];
                d0 += mh[k8].x * k.x;
                d1 += mh[k8].y * k.y;
                d2 += mh[k8].z * k.z;
                d3 += mh[k8].w * k.w;
            }
            float dot = (d0 + d1) + (d2 + d3);
            float sim = dot / (rown * knR + EPSF);
            float ev = __expf(betaR * sim);
            sh_evwp[tid] = make_float2(ev, rwprev);
            float s = rowsum64(ev);
            if (lane == 63) red[2][wv] = s;
        }
        BAR();  // 7
        // ===== I: conv + sharpen (read); transpose partials =====
        float wshR;
        {
            const float4* rp = (const float4*)red[2];
            float Sev = 0.0f;
            #pragma unroll
            for (int w4 = 0; w4 < 4; ++w4) { float4 p = rp[w4]; Sev += p.x + p.y + p.z + p.w; }
            int tm1 = (tid + NN - 1) & (NN - 1), tp1 = (tid + 1) & (NN - 1);
            float2 em1 = sh_evwp[tm1], ec = sh_evwp[tid], ep1 = sh_evwp[tp1];
            float cEV = s0R * em1.x + s1R * ec.x + s2R * ep1.x;
            float cWP = s0R * em1.y + s1R * ec.y + s2R * ep1.y;
            float ws = (gR / Sev) * cEV + (1.0f - gR) * cWP;
            wshR = pow_f(ws, gamR);
            float s = rowsum64(wshR);
            if (lane == 63) red[3][wv] = s;
            #pragma unroll
            for (int chunk = 0; chunk < 4; ++chunk) {
                const int cb = chunk * 16;
                float v[16];
                if (chunk < 2) {
                    #pragma unroll
                    for (int i = 0; i < 16; ++i) v[i] = wshR * Mlo[chunk * 16 + i];
                } else {
                    #pragma unroll
                    for (int k = 0; k < 4; ++k) {
                        float4 m = mh[(chunk - 2) * 4 + k];
                        v[4*k]   = wshR * m.x;
                        v[4*k+1] = wshR * m.y;
                        v[4*k+2] = wshR * m.z;
                        v[4*k+3] = wshR * m.w;
                    }
                }
                #pragma unroll
                for (int st = 0; st < 4; ++st) {
                    const int m = 1 << st;
                    const int hs = 8 >> st;
                    bool hi = (lane & m) != 0;
                    #pragma unroll
                    for (int i = 0; i < 8; ++i) {
                        if (i < hs) {
                            float send = hi ? v[i] : v[i + hs];
                            float recv = xor_any(send, m, lane);
                            float keep = hi ? v[i + hs] : v[i];
                            v[i] = keep + recv;
                        }
                    }
                }
                float v0 = v[0];
                v0 += xor_any(v0, 16, lane);
                v0 += xor_any(v0, 32, lane);
                if (lane < 16) wmat[wv][cb + bitrev4(lane)] = v0;
            }
        }
        BAR();  // 8
        // ===== J: normalize rwn + finalize; commit pre[t+1] prefetch to LDS =====
        {
            if (wv >= 6 && wv < 14 && t + 1 < TT) sh_pren[tid - 384] = pren_v;
            const float4* rp = (const float4*)red[3];
            float Swsh = 0.0f;
            #pragma unroll
            for (int w4 = 0; w4 < 4; ++w4) { float4 p = rp[w4]; Swsh += p.x + p.y + p.z + p.w; }
            float inv = 1.0f / (Swsh + EPSF);
            float rwn = wshR * inv;
            out[OFF_RW + t * NN + tid] = rwn;
            rwprev = rwn;
            if (tid < MM) {
                float rv = 0.0f;
                #pragma unroll
                for (int w = 0; w < 16; ++w) rv += wmat[w][tid];
                rv *= inv;
                sh_r[tid] = rv;
                out[OFF_R + t * MM + tid] = rv;
            }
        }
        BAR();  // 9
        // (K for this step runs one step late, in phase C on wave 15)
    }

    // Epilogue: K for t = TT-1 (sh_r still holds r(TT-1))
    if (tid < LL) {
        const float4* r4p = (const float4*)sh_r;
        const float4* wop = (const float4*)(sh_WoT + tid * WOT_S);
        float a0 = 0.0f, a1 = 0.0f;
        #pragma unroll
        for (int i4 = 0; i4 < 16; ++i4) {
            float4 r = r4p[i4];
            float4 w = wop[i4];
            a0 += r.x * w.x + r.y * w.y;
            a1 += r.z * w.z + r.w * w.w;
        }
        float acc = sh_bo[tid] + a0 + a1;
        out[OFF_SEQ + (TT - 1) * LL + tid] = fminf(fmaxf(acc, 0.0f), 1.0f);
    }
}

extern "C" void kernel_launch(void* const* d_in, const int* in_sizes, int n_in,
                              void* d_out, int out_size, void* d_ws, size_t ws_size,
                              hipStream_t stream) {
    const float* seq = (const float*)d_in[0];
    const float* Wc  = (const float*)d_in[1];
    const float* bc  = (const float*)d_in[2];
    const float* Wr  = (const float*)d_in[3];
    const float* br  = (const float*)d_in[4];
    const float* Ww  = (const float*)d_in[5];
    const float* bw  = (const float*)d_in[6];
    const float* Wo  = (const float*)d_in[7];
    const float* bo  = (const float*)d_in[8];
    float* out = (float*)d_out;

    float* wsf  = (float*)d_ws;
    float* pre  = wsf + WSF_PRE;
    float* Wcat = wsf + WSF_WCAT;

    pre_kernel<<<(TT * CC) / 256, 256, 0, stream>>>(seq, Wc, bc, pre);
    pack_kernel<<<(512 * 272 + 255) / 256, 256, 0, stream>>>(Ww, Wr, Wcat);
    ntm_kernel<<<1, 1024, 0, stream>>>(pre, Wc, Wcat, br, bw, Wo, bo, out);
}